// Round 10
// baseline (94.849 us; speedup 1.0000x reference)
//
#include <hip/hip_runtime.h>

// SparseLookupTable via one-hot MFMA (data conventions HW-verified rounds 1-9):
//   out[b,o] = sum_k lut[inp[b,k], wgt[o,k]],  B=512, O=1024, K=128, LUT 256x256.
//   A_k[b, j] = lut[inp[b,k], j]   (f16 rows gathered from LDS, ds_read_b128)
//   B_k[j, o] = onehot(wgt[o,k])   (built in VALU registers)
// MFMA f32_16x16x32_f16, 8 K-steps of 32 cover the 256-wide one-hot dim.
//
// Round-10: latency/overlap attack; zero math changes vs round-8.
//   Cross-round A/B (r2 vs r8) showed A-gather marginal cost ~17cyc/read and
//   select-VALU mostly hidden -> regime is latency-bound at 4 waves/SIMD with
//   `unroll 1` walling each kslice's dependent chain (u16 -> addr -> 8x b128).
//   (1) Fully unroll j (8x): scheduler hoists next-kslice index reads and
//       gather issues across iterations with counted lgkmcnt.
//   (2) __launch_bounds__(1024, 4): min 4 waves/EU == true occupancy ->
//       128-VGPR budget for the widened live ranges (r8/r9 sat at 64).

#define KDIM 128

typedef _Float16 f16x8 __attribute__((ext_vector_type(8)));
typedef float    f32x4 __attribute__((ext_vector_type(4)));

union F16Frag { uint4 u; f16x8 h; };

__global__ __launch_bounds__(1024, 4)
void slt_mfma(const int* __restrict__ inp, const int* __restrict__ wgt,
              const float* __restrict__ lut, float* __restrict__ out)
{
    // 131072 (LUT f16 swizzled) + 2048 (i_lds [128][16] u8)
    // + 16384 (w_lds [128][16][8] u8) = 149504 B  (red reuses LUT region)
    __shared__ __attribute__((aligned(16))) unsigned char smem[149504];
    unsigned char* lutB  = smem;
    unsigned char* i_lds = smem + 131072;
    unsigned char* w_lds = smem + 133120;

    const int tid   = threadIdx.x;
    const int otile = blockIdx.x;   // 8 tiles of 128 outputs
    const int btile = blockIdx.y;   // 32 tiles of 16 batch rows

    // ---- stage LUT fp32 -> fp16, chunk-XOR swizzled (verbatim r3-r9) ----
    // row r, logical byte lb (512/row), chunk = lb>>4 (16B units).
    // phys = r*512 + (((chunk&24) | ((chunk ^ (r&7)) & 7)) << 4) + (lb & 15)
    {
        const float4* lut4 = (const float4*)lut;
        #pragma unroll
        for (int it = 0; it < 16; ++it) {
            int idx = it * 1024 + tid;
            float4 v = lut4[idx];
            union { _Float16 h[4]; unsigned long long u; } pk;
            pk.h[0] = (_Float16)v.x; pk.h[1] = (_Float16)v.y;
            pk.h[2] = (_Float16)v.z; pk.h[3] = (_Float16)v.w;
            unsigned r  = (unsigned)idx >> 6;
            unsigned lb = ((unsigned)idx & 63u) << 3;
            unsigned ch = lb >> 4;
            unsigned sw = (ch & 24u) | ((ch ^ (r & 7u)) & 7u);
            unsigned off = (r << 9) + (sw << 4) + (lb & 15u);
            *(unsigned long long*)(lutB + off) = pk.u;
        }
    }

    // ---- stage i: i_lds[k*16 + row] = inp[btile*16+row][k] & 255 ----
    if (tid < 512) {
        int row = tid >> 5;            // 0..15
        int c4  = tid & 31;            // int4 group over K=128
        int4 iv = *(const int4*)(inp + (size_t)(btile * 16 + row) * KDIM + c4 * 4);
        int k0 = c4 * 4;
        i_lds[(k0+0)*16 + row] = (unsigned char)(iv.x & 255);
        i_lds[(k0+1)*16 + row] = (unsigned char)(iv.y & 255);
        i_lds[(k0+2)*16 + row] = (unsigned char)(iv.z & 255);
        i_lds[(k0+3)*16 + row] = (unsigned char)(iv.w & 255);
    }

    // ---- stage w: w_lds[k*128 + colq*8 + nt] = wgt[otile*128+nt*16+colq][k] ----
    {
        int o  = tid >> 3;             // 0..127 output within tile
        int kq = tid & 7;              // 8 groups of 16 k each
        const int* wp = wgt + (size_t)(otile * 128 + o) * KDIM + kq * 16;
        unsigned char* wb = w_lds + (o & 15) * 8 + (o >> 4);
        #pragma unroll
        for (int g = 0; g < 4; ++g) {
            int4 wv4 = *(const int4*)(wp + g * 4);
            int kb = kq * 16 + g * 4;
            wb[(kb+0)*128] = (unsigned char)(wv4.x & 255);
            wb[(kb+1)*128] = (unsigned char)(wv4.y & 255);
            wb[(kb+2)*128] = (unsigned char)(wv4.z & 255);
            wb[(kb+3)*128] = (unsigned char)(wv4.w & 255);
        }
    }
    __syncthreads();

    const int      lane = tid & 63;
    const int      wid  = tid >> 6;                 // 8 kslices: wid*8 .. wid*8+7
    const unsigned colq = (unsigned)(lane & 15);    // A row-lane / B col / D col
    const unsigned q    = (unsigned)((lane >> 4) & 3);
    const unsigned h8   = q << 3;                   // k-subgroup * 8

    f32x4 acc[8];
    #pragma unroll
    for (int n = 0; n < 8; ++n) { f32x4 z = {0.f,0.f,0.f,0.f}; acc[n] = z; }

    #pragma unroll
    for (int j = 0; j < 8; ++j) {
        const int ks = wid * 8 + j;            // kslice 0..127 (full K)

        // A row for this lane's M-row (single 16-row M-tile)
        unsigned r0 = (unsigned)i_lds[ks * 16 + colq];
        unsigned L0 = q ^ (r0 & 7u);
        const unsigned char* pA  = lutB + ((r0 << 9) + (L0 << 4));
        const unsigned char* pAo = pA + 64u - ((L0 & 4u) << 5);

        // One-hot prep for 8 N-tiles from one b64 read (r3 sl/p scheme, verbatim)
        unsigned long long wq =
            *(const unsigned long long*)(w_lds + ks * 128 + colq * 8);
        unsigned wlo = (unsigned)wq, whi = (unsigned)(wq >> 32);

        unsigned p[8][4]; unsigned sl[8];
        #pragma unroll
        for (int nt = 0; nt < 8; ++nt) {
            unsigned wv = ((nt < 4 ? wlo : whi) >> ((nt & 3) * 8)) & 255u;
            unsigned u    = wv - h8;
            unsigned slot = u & 7u;
            unsigned long long pk = 0x3C00ULL << ((slot & 3u) << 4);
            unsigned lo = (unsigned)pk, hi = (unsigned)(pk >> 32);
            unsigned lh    = (slot < 4u);
            unsigned valid = ((u & 31u) < 8u);
            sl[nt] = valid ? (u >> 5) : 0xFFu;
            p[nt][0] = lh ? lo : 0u;
            p[nt][1] = lh ? hi : 0u;
            p[nt][2] = lh ? 0u : lo;
            p[nt][3] = lh ? 0u : hi;
        }

        // 8 MFMA K-steps; one A-read feeds all 8 nt
        #pragma unroll
        for (int s = 0; s < 8; ++s) {
            F16Frag a0;
            a0.u = *(const uint4*)((((unsigned)s & 1u) ? pAo : pA)
                                   + ((unsigned)s >> 1) * 128u);
            #pragma unroll
            for (int nt = 0; nt < 8; ++nt) {
                F16Frag bb;
                bool take = (sl[nt] == (unsigned)s);
                bb.u.x = take ? p[nt][0] : 0u;
                bb.u.y = take ? p[nt][1] : 0u;
                bb.u.z = take ? p[nt][2] : 0u;
                bb.u.w = take ? p[nt][3] : 0u;
                acc[nt] = __builtin_amdgcn_mfma_f32_16x16x32_f16(a0.h, bb.h, acc[nt], 0, 0, 0);
            }
        }
    }

    // ---- one-shot 16-way cross-wave reduction in dead LUT LDS + store ----
    __syncthreads();                      // all waves done reading lutB
    f32x4* red = (f32x4*)smem;            // [wid][nt][lane] = 16*8*64*16B = 128 KB
    #pragma unroll
    for (int nt = 0; nt < 8; ++nt)
        red[(wid * 8 + nt) * 64 + lane] = acc[nt];
    __syncthreads();

    if (tid < 512) {
        const int nt = tid >> 6, ln = tid & 63;
        f32x4 s4 = {0.f, 0.f, 0.f, 0.f};
        #pragma unroll
        for (int w = 0; w < 16; ++w)
            s4 += red[(w * 8 + nt) * 64 + ln];
        // D layout: col = lane&15, row = (lane>>4)*4 + reg  (HW-verified)
        const int rrow = btile * 16 + ((ln >> 4) & 3) * 4;
        const int ccol = otile * 128 + nt * 16 + (ln & 15);
        #pragma unroll
        for (int c = 0; c < 4; ++c)
            out[(size_t)(rrow + c) * 1024 + ccol] = s4[c];
    }
}

extern "C" void kernel_launch(void* const* d_in, const int* in_sizes, int n_in,
                              void* d_out, int out_size, void* d_ws, size_t ws_size,
                              hipStream_t stream) {
    const int*   inp = (const int*)d_in[0];    // (512, 32, 4) int32
    const int*   wgt = (const int*)d_in[1];    // (1024, 32, 4) int32
    const float* lut = (const float*)d_in[2];  // (256, 256) fp32
    float*       out = (float*)d_out;          // (512, 1024) fp32

    dim3 grid(8, 32);
    dim3 block(1024);
    slt_mfma<<<grid, block, 0, stream>>>(inp, wgt, lut, out);
}